// Round 6
// baseline (241.583 us; speedup 1.0000x reference)
//
#include <hip/hip_runtime.h>
#include <hip/hip_cooperative_groups.h>

namespace cg = cooperative_groups;

#define NN 4096
#define COL4 (NN / 4)      // 1024 float4 per row
#define BB 8
#define F_IN 40
#define HH 64
#define KW 5
#define LL (NN - KW + 1)   // 4092
#define RC 32              // row chunks for A passes (128 rows each)
#define CHUNK (NN / RC)    // 128
#define PCB 64             // phase-C chunks per batch
#define PCH 64             // rows per chunk
#define PCH4 (PCH / 4)     // 16

// workspace layout (floats)
#define OFF_P1 0                           // [RC][NN]     partial colsums
#define OFF_PE (OFF_P1 + RC * NN)          // [RC][8][NN]  partial e_s
#define OFF_PD (OFF_PE + RC * 8 * NN)      // [RC][NN]     partial d
#define OFF_XP (OFF_PD + RC * NN)          // [64][9][64]  X partials (stride 576)
#define OFF_BW (OFF_XP + 64 * 576)         // [64]         bw2
#define OFF_M  (OFF_BW + 64)               // [9][F_IN]
#define OFF_AB (OFF_M + 9 * F_IN)          // [9]
#define OFF_G9 (OFF_AB + 9)                // [9]
#define OFF_RP (OFF_G9 + 9)                // [8][16]
#define OFF_SC (OFF_RP + 128)              // [32]
#define OFF_SP (OFF_SC + 32)               // [BB][64]

#define SMEM_BYTES 33280

__device__ __forceinline__ int special_row(int s) { return s < 4 ? s : (NN - 8 + s); }
__device__ __forceinline__ void f4add(float4& a, const float4& b) {
    a.x += b.x; a.y += b.y; a.z += b.z; a.w += b.w;
}
__device__ __forceinline__ void f4fma(float4& a, float w, const float4& b) {
    a.x += w * b.x; a.y += w * b.y; a.z += w * b.z; a.w += w * b.w;
}

__global__ __launch_bounds__(256, 2) void kFused(
    const float* __restrict__ A, const float* __restrict__ x,
    const float* __restrict__ W1, const float* __restrict__ b1,
    const float* __restrict__ W2, const float* __restrict__ b2,
    const float* __restrict__ cw, const float* __restrict__ cb,
    const float* __restrict__ fw, const float* __restrict__ fb,
    float* __restrict__ ws, float* __restrict__ out)
{
    __shared__ __align__(16) char smem[SMEM_BYTES];
    const float4* A4 = (const float4*)A;
    float* part1 = ws + OFF_P1;
    float* partE = ws + OFF_PE;
    float* partD = ws + OFF_PD;
    float* Xpart = ws + OFF_XP;
    float* bw2   = ws + OFF_BW;
    float* Mp    = ws + OFF_M;
    float* ABp   = ws + OFF_AB;
    float* G9p   = ws + OFF_G9;
    float* rpart = ws + OFF_RP;
    float* sCp   = ws + OFF_SC;
    float* spart = ws + OFF_SP;

    const int bid = blockIdx.x;
    const int tid = threadIdx.x;
    const int tx = tid & 63, ty = tid >> 6;
    cg::grid_group grid = cg::this_grid();

    // ================= Phase A: stream A -> colsum + e_s partials =================
    {
        float* wsh = (float*)smem;                              // [8][128]
        float4 (*red3)[3][64] = (float4 (*)[3][64])(smem + 4096);
        const int bx = bid & 15, by = bid >> 4;
        const int m0 = by * CHUNK;
        for (int idx = tid; idx < 8 * CHUNK; idx += 256) {
            int s = idx >> 7, j = idx & 127;
            wsh[s * CHUNK + j] = A[(size_t)special_row(s) * NN + m0 + j];
        }
        __syncthreads();
        const int c4 = bx * 64 + tx;
        const float4* Ap = A4 + (size_t)(m0 + ty * 32) * COL4 + c4;
        float4 acc[9];
        #pragma unroll
        for (int v = 0; v < 9; ++v) acc[v] = make_float4(0.f, 0.f, 0.f, 0.f);
        #pragma unroll 4
        for (int j = 0; j < 32; ++j) {
            float4 a = Ap[(size_t)j * COL4];
            int jj = ty * 32 + j;
            f4add(acc[0], a);
            #pragma unroll
            for (int s = 0; s < 8; ++s) f4fma(acc[1 + s], wsh[s * CHUNK + jj], a);
        }
        #pragma unroll
        for (int g = 0; g < 3; ++g) {
            #pragma unroll
            for (int vv = 0; vv < 3; ++vv) red3[ty][vv][tx] = acc[g * 3 + vv];
            __syncthreads();
            if (ty == 0) {
                #pragma unroll
                for (int vv = 0; vv < 3; ++vv) {
                    int v = g * 3 + vv;
                    float4 t = red3[0][vv][tx];
                    f4add(t, red3[1][vv][tx]);
                    f4add(t, red3[2][vv][tx]);
                    f4add(t, red3[3][vv][tx]);
                    if (v == 0) ((float4*)part1)[(size_t)by * COL4 + c4] = t;
                    else        ((float4*)partE)[((size_t)by * 8 + (v - 1)) * COL4 + c4] = t;
                }
            }
            __syncthreads();
        }
        if ((by == 0 || by == 31) && ty == 0) {
            int sbase = (by == 0) ? 0 : 4;
            #pragma unroll
            for (int k = 0; k < 4; ++k) {
                float4 a = A4[(size_t)special_row(sbase + k) * COL4 + c4];
                float v = a.x + a.y + a.z + a.w;
                for (int off = 32; off > 0; off >>= 1) v += __shfl_down(v, off);
                if (tx == 0) rpart[(sbase + k) * 16 + bx] = v;
            }
        }
        if (bid < 64 && tid < 64) {
            int o = bid, i = tid;
            float f = fw[o];
            const float* cwp = cw + ((size_t)o * HH + i) * KW;
            float w0 = cwp[0], w1 = cwp[1], w2 = cwp[2], w3 = cwp[3], w4 = cwp[4];
            float* xp = Xpart + (size_t)o * 576 + i;
            xp[0]   = f * (w0 + w1 + w2 + w3 + w4);
            xp[64]  = f * (w1 + w2 + w3 + w4);
            xp[128] = f * (w2 + w3 + w4);
            xp[192] = f * (w3 + w4);
            xp[256] = f * w4;
            xp[320] = f * w0;
            xp[384] = f * (w0 + w1);
            xp[448] = f * (w0 + w1 + w2);
            xp[512] = f * (w0 + w1 + w2 + w3);
        }
        if (bid == 64) {
            float* W2s = (float*)(smem + 16384);   // [64][65]
            float* b1s = (float*)(smem + 16384 + 16640);
            for (int idx = tid; idx < 64 * 64; idx += 256)
                W2s[(idx >> 6) * 65 + (idx & 63)] = W2[idx];
            if (tid < 64) b1s[tid] = b1[tid];
            __syncthreads();
            if (tid < 64) {
                float s = 0.f;
                #pragma unroll 8
                for (int h = 0; h < 64; ++h) s += b1s[h] * W2s[h * 65 + tid];
                bw2[tid] = s;
            }
        }
    }
    grid.sync();
    // ================= Phase B: stream A -> d partials; adjoint tail =================
    {
        const int bx = bid & 15, by = bid >> 4;
        float* cs = (float*)smem;                    // [128]
        float4 (*redd)[64] = (float4 (*)[64])(smem + 512);
        const int m0 = by * CHUNK;
        if (tid < CHUNK) {
            float s = 0.f;
            #pragma unroll 8
            for (int y = 0; y < RC; ++y) s += part1[(size_t)y * NN + m0 + tid];
            cs[tid] = s;
        }
        __syncthreads();
        if (bx == 0 && tid < 64) {
            float t = cs[tid] + cs[tid + 64];
            for (int off = 32; off > 0; off >>= 1) t += __shfl_down(t, off);
            if (tid == 0) sCp[by] = t;
        }
        const int c4 = bx * 64 + tx;
        const float4* Ap = A4 + (size_t)(m0 + ty * 32) * COL4 + c4;
        float4 acc = {0.f, 0.f, 0.f, 0.f};
        #pragma unroll 8
        for (int j = 0; j < 32; ++j) f4fma(acc, cs[ty * 32 + j], Ap[(size_t)j * COL4]);
        redd[ty][tx] = acc;
        __syncthreads();
        if (ty == 0) {
            float4 t = redd[0][tx];
            f4add(t, redd[1][tx]);
            f4add(t, redd[2][tx]);
            f4add(t, redd[3][tx]);
            ((float4*)partD)[(size_t)by * COL4 + c4] = t;
        }
        // adjoint tail: blocks 0..8, one per v, after their streaming work
        if (bid < 9) {
            int v = bid;
            float* W2s = (float*)(smem + 4608);            // [64][65]
            float* W1s = (float*)(smem + 4608 + 16640);    // [40][65] @21248
            float* Xs  = (float*)(smem + 21248 + 10400);   // @31648
            float* Ps  = Xs + 64;
            float* bw2s = Ps + 64;
            float* b2s  = bw2s + 64;
            float* fcb  = b2s + 64;
            __syncthreads();
            for (int idx = tid; idx < 64 * 64; idx += 256)
                W2s[(idx >> 6) * 65 + (idx & 63)] = W2[idx];
            for (int idx = tid; idx < 40 * 64; idx += 256)
                W1s[(idx >> 6) * 65 + (idx & 63)] = W1[idx];
            if (tid < 64) { bw2s[tid] = bw2[tid]; b2s[tid] = b2[tid]; }
            if (tid == 0) fcb[0] = 0.f;
            __syncthreads();
            if (tid < 64) {
                float s = 0.f;
                #pragma unroll 8
                for (int o = 0; o < 64; ++o) s += Xpart[(size_t)o * 576 + v * 64 + tid];
                Xs[tid] = (v == 0 ? 1.f : -1.f) * s / (float)LL;
            }
            __syncthreads();
            if (tid < 64) {
                float s = 0.f;
                #pragma unroll 8
                for (int i = 0; i < 64; ++i) s += Xs[i] * W2s[tid * 65 + i];
                Ps[tid] = s;
            }
            __syncthreads();
            if (tid < F_IN) {
                float s = 0.f;
                #pragma unroll 8
                for (int h = 0; h < 64; ++h) s += Ps[h] * W1s[tid * 65 + h];
                Mp[v * F_IN + tid] = s;
            }
            if (tid >= 64 && tid < 128) {
                int i = tid - 64;
                float a = Xs[i] * bw2s[i];
                for (int off = 32; off > 0; off >>= 1) a += __shfl_down(a, off);
                if (i == 0) ABp[v] = a;
            }
            if (v == 0 && tid >= 128 && tid < 192) {
                int o = tid - 128;
                float t = fw[o] * cb[o];
                for (int off = 32; off > 0; off >>= 1) t += __shfl_down(t, off);
                if (o == 0) fcb[0] = t;
            }
            __syncthreads();
            if (tid < 64) {
                float g = Xs[tid] * (v == 0 ? (float)NN * b2s[tid] : b2s[tid]);
                for (int off = 32; off > 0; off >>= 1) g += __shfl_down(g, off);
                if (tid == 0) G9p[v] = g + (v == 0 ? fcb[0] + fb[0] : 0.f);
            }
        }
    }
    grid.sync();
    // ================= Phase C: x-contraction, 512 blocks = (b, pc) =================
    {
        const int b = bid >> 6, pc = bid & 63;
        float* xs  = (float*)smem;                       // [64][40]
        float* wls = (float*)(smem + 10240);             // [9][68] padded
        float* Ms  = (float*)(smem + 10240 + 2448);      // [360] @12688
        float* red = (float*)(smem + 12688 + 1440);      // [256] @14128
        const int p0 = pc * PCH;
        const float4* xsrc4 = (const float4*)(x + ((size_t)b * NN + p0) * F_IN);
        float4* xs4 = (float4*)xs;
        for (int idx = tid; idx < PCH * F_IN / 4; idx += 256) xs4[idx] = xsrc4[idx];
        for (int idx = tid; idx < 9 * PCH4; idx += 256) {
            int v = idx / PCH4, j4 = idx % PCH4;
            float4 s = {0.f, 0.f, 0.f, 0.f};
            if (v == 0) {
                #pragma unroll 8
                for (int y = 0; y < RC; ++y)
                    f4add(s, ((const float4*)partD)[(size_t)y * COL4 + pc * PCH4 + j4]);
            } else {
                #pragma unroll 8
                for (int y = 0; y < RC; ++y)
                    f4add(s, ((const float4*)partE)[((size_t)y * 8 + (v - 1)) * COL4 + pc * PCH4 + j4]);
            }
            *(float4*)&wls[v * 68 + j4 * 4] = s;
        }
        for (int idx = tid; idx < 9 * F_IN; idx += 256) Ms[idx] = Mp[idx];
        __syncthreads();
        float part = 0.f;
        for (int o = tid; o < 9 * F_IN; o += 256) {
            int v = o / F_IN, f = o % F_IN;
            float s = 0.f;
            #pragma unroll 8
            for (int j = 0; j < PCH; ++j) s += wls[v * 68 + j] * xs[j * F_IN + f];
            part += Ms[o] * s;
        }
        red[tid] = part;
        __syncthreads();
        for (int off = 128; off > 0; off >>= 1) {
            if (tid < off) red[tid] += red[tid + off];
            __syncthreads();
        }
        if (tid == 0) spart[(size_t)b * 64 + pc] = red[0];
    }
    grid.sync();
    // ================= Phase D: finish =================
    if (bid == 0) {
        float* red = (float*)smem;   // [128]
        if (tid < 128) {
            float val = ABp[1 + (tid >> 4)] * rpart[tid];
            if (tid < 32) val += ABp[0] * sCp[tid];
            if (tid < 9)  val += G9p[tid];
            red[tid] = val;
        }
        __syncthreads();
        for (int off = 64; off > 0; off >>= 1) {
            if (tid < off) red[tid] += red[tid + off];
            __syncthreads();
        }
        float c0 = red[0];
        int b = tid >> 5, l = tid & 31;
        float s = spart[(size_t)b * 64 + l] + spart[(size_t)b * 64 + 32 + l];
        for (int off = 16; off > 0; off >>= 1) s += __shfl_down(s, off, 32);
        if (l == 0) out[b] = c0 + s;
    }
}

extern "C" void kernel_launch(void* const* d_in, const int* in_sizes, int n_in,
                              void* d_out, int out_size, void* d_ws, size_t ws_size,
                              hipStream_t stream) {
    const float* x  = (const float*)d_in[0];
    const float* A  = (const float*)d_in[1];
    const float* W1 = (const float*)d_in[2];
    const float* b1 = (const float*)d_in[3];
    const float* W2 = (const float*)d_in[4];
    const float* b2 = (const float*)d_in[5];
    const float* cw = (const float*)d_in[6];
    const float* cb = (const float*)d_in[7];
    const float* fw = (const float*)d_in[8];
    const float* fb = (const float*)d_in[9];
    float* out = (float*)d_out;
    float* ws  = (float*)d_ws;

    void* args[] = {(void*)&A, (void*)&x, (void*)&W1, (void*)&b1, (void*)&W2, (void*)&b2,
                    (void*)&cw, (void*)&cb, (void*)&fw, (void*)&fb, (void*)&ws, (void*)&out};
    hipLaunchCooperativeKernel((void*)kFused, dim3(512), dim3(256), args, 0, stream);
}

// Round 7
// 72.160 us; speedup vs baseline: 3.3479x; 3.3479x over previous
//
#include <hip/hip_runtime.h>

#define NN 4096
#define COL4 (NN / 4)      // 1024 float4 per row
#define BB 8
#define F_IN 40
#define HH 64
#define KW 5
#define LL (NN - KW + 1)   // 4092
#define RC 32              // row chunks for A passes (128 rows each)
#define CHUNK (NN / RC)    // 128

// workspace layout (floats)
#define OFF_P1 0                           // [RC][NN]     partial colsums
#define OFF_PE (OFF_P1 + RC * NN)          // [RC][8][NN]  partial e_s
#define OFF_PD (OFF_PE + RC * 8 * NN)      // [RC][NN]     partial d
#define OFF_XP (OFF_PD + RC * NN)          // [64][9][64]  X partials (stride 576)
#define OFF_BW (OFF_XP + 64 * 576)         // [64]         bw2
#define OFF_M  (OFF_BW + 64)               // [9][F_IN]    adjoint map M
#define OFF_RP (OFF_M + 9 * F_IN)          // [8][16]      rpart
#define OFF_SCS (OFF_RP + 128)             // [1]          sC atomic accumulator

__device__ __forceinline__ int special_row(int s) { return s < 4 ? s : (NN - 8 + s); }
__device__ __forceinline__ void f4add(float4& a, const float4& b) {
    a.x += b.x; a.y += b.y; a.z += b.z; a.w += b.w;
}
__device__ __forceinline__ void f4fma(float4& a, float w, const float4& b) {
    a.x += w * b.x; a.y += w * b.y; a.z += w * b.z; a.w += w * b.w;
}

// kA: blocks 0..511 stream A (colsum + e_s partials + rpart + sC atomic);
//     blocks 512..575: X-partials; block 576: bw2. grid 577, block (64,4).
__global__ __launch_bounds__(256) void kA(const float4* __restrict__ A4,
                                          const float* __restrict__ A,
                                          float4* __restrict__ part1,
                                          float4* __restrict__ partE,
                                          float* __restrict__ rpart,
                                          float* __restrict__ sCsum,
                                          const float* __restrict__ b1,
                                          const float* __restrict__ W2,
                                          const float* __restrict__ cw,
                                          const float* __restrict__ fw,
                                          float* __restrict__ Xpart,
                                          float* __restrict__ bw2) {
    int tx = threadIdx.x, ty = threadIdx.y;
    int tid = ty * 64 + tx;
    if (blockIdx.x < 512) {
        __shared__ float wsh[8][CHUNK];        // 4 KB
        __shared__ float4 red3[4][3][64];      // 12 KB
        const int bx = blockIdx.x & 15, by = blockIdx.x >> 4;
        const int m0 = by * CHUNK;
        for (int idx = tid; idx < 8 * CHUNK; idx += 256) {
            int s = idx >> 7, j = idx & 127;
            wsh[s][j] = A[(size_t)special_row(s) * NN + m0 + j];
        }
        __syncthreads();
        const int c4 = bx * 64 + tx;
        const float4* Ap = A4 + (size_t)(m0 + ty * 32) * COL4 + c4;
        float4 acc[9];
        #pragma unroll
        for (int v = 0; v < 9; ++v) acc[v] = make_float4(0.f, 0.f, 0.f, 0.f);
        #pragma unroll 4
        for (int j = 0; j < 32; ++j) {
            float4 a = Ap[(size_t)j * COL4];
            int jj = ty * 32 + j;
            f4add(acc[0], a);
            #pragma unroll
            for (int s = 0; s < 8; ++s) f4fma(acc[1 + s], wsh[s][jj], a);
        }
        #pragma unroll
        for (int g = 0; g < 3; ++g) {
            #pragma unroll
            for (int vv = 0; vv < 3; ++vv) red3[ty][vv][tx] = acc[g * 3 + vv];
            __syncthreads();
            if (ty == 0) {
                #pragma unroll
                for (int vv = 0; vv < 3; ++vv) {
                    int v = g * 3 + vv;
                    float4 t = red3[0][vv][tx];
                    f4add(t, red3[1][vv][tx]);
                    f4add(t, red3[2][vv][tx]);
                    f4add(t, red3[3][vv][tx]);
                    if (v == 0) {
                        part1[(size_t)by * COL4 + c4] = t;
                        // block's contribution to sC = sum of all of A
                        float val = t.x + t.y + t.z + t.w;
                        for (int off = 32; off > 0; off >>= 1) val += __shfl_down(val, off);
                        if (tx == 0) atomicAdd(sCsum, val);
                    } else {
                        partE[((size_t)by * 8 + (v - 1)) * COL4 + c4] = t;
                    }
                }
            }
            __syncthreads();
        }
        if ((by == 0 || by == 31) && ty == 0) {
            int sbase = (by == 0) ? 0 : 4;
            #pragma unroll
            for (int k = 0; k < 4; ++k) {
                float4 a = A4[(size_t)special_row(sbase + k) * COL4 + c4];
                float v = a.x + a.y + a.z + a.w;
                for (int off = 32; off > 0; off >>= 1) v += __shfl_down(v, off);
                if (tx == 0) rpart[(sbase + k) * 16 + bx] = v;
            }
        }
        return;
    }
    if (blockIdx.x < 576) {
        int o = blockIdx.x - 512;
        if (tid < 64) {
            int i = tid;
            float f = fw[o];
            const float* cwp = cw + ((size_t)o * HH + i) * KW;
            float w0 = cwp[0], w1 = cwp[1], w2 = cwp[2], w3 = cwp[3], w4 = cwp[4];
            float* xp = Xpart + (size_t)o * 576 + i;
            xp[0]   = f * (w0 + w1 + w2 + w3 + w4);
            xp[64]  = f * (w1 + w2 + w3 + w4);
            xp[128] = f * (w2 + w3 + w4);
            xp[192] = f * (w3 + w4);
            xp[256] = f * w4;
            xp[320] = f * w0;
            xp[384] = f * (w0 + w1);
            xp[448] = f * (w0 + w1 + w2);
            xp[512] = f * (w0 + w1 + w2 + w3);
        }
        return;
    }
    // block 576: bw2[i] = sum_h b1[h] * W2[h,i] (coalesced per-h row reads)
    {
        __shared__ float b1s[64];
        if (tid < 64) b1s[tid] = b1[tid];
        __syncthreads();
        if (tid < 64) {
            float s = 0.f;
            #pragma unroll 8
            for (int h = 0; h < 64; ++h) s += b1s[h] * W2[h * HH + tid];
            bw2[tid] = s;
        }
    }
}

// kC: blocks 0..511 stream A for d-partials; block 512: full adjoint + c0 seed.
// grid 513, block 256
__global__ __launch_bounds__(256) void kC(const float4* __restrict__ A4,
                                          const float* __restrict__ part1f,
                                          float4* __restrict__ partD,
                                          const float* __restrict__ Xpart,
                                          const float* __restrict__ bw2g,
                                          const float* __restrict__ rpart,
                                          const float* __restrict__ sCsum,
                                          const float* __restrict__ W1,
                                          const float* __restrict__ W2,
                                          const float* __restrict__ b2,
                                          const float* __restrict__ cb,
                                          const float* __restrict__ fw,
                                          const float* __restrict__ fb,
                                          float* __restrict__ Mout,
                                          float* __restrict__ out) {
    int tid = threadIdx.x;
    if (blockIdx.x < 512) {
        const int bx = blockIdx.x & 15, by = blockIdx.x >> 4;
        const int tx = tid & 63, ty = tid >> 6;
        __shared__ float cs[CHUNK];
        __shared__ float4 redd[4][64];
        const int m0 = by * CHUNK;
        if (tid < CHUNK) {
            float s = 0.f;
            #pragma unroll 8
            for (int y = 0; y < RC; ++y) s += part1f[(size_t)y * NN + m0 + tid];
            cs[tid] = s;
        }
        __syncthreads();
        const int c4 = bx * 64 + tx;
        const float4* Ap = A4 + (size_t)(m0 + ty * 32) * COL4 + c4;
        float4 acc = {0.f, 0.f, 0.f, 0.f};
        #pragma unroll 8
        for (int j = 0; j < 32; ++j) f4fma(acc, cs[ty * 32 + j], Ap[(size_t)j * COL4]);
        redd[ty][tx] = acc;
        __syncthreads();
        if (ty == 0) {
            float4 t = redd[0][tx];
            f4add(t, redd[1][tx]);
            f4add(t, redd[2][tx]);
            f4add(t, redd[3][tx]);
            partD[(size_t)by * COL4 + c4] = t;
        }
        return;
    }
    // ---- single adjoint block: all v, M, c0, out-seed ----
    __shared__ float W2s[64 * 65];    // 16.6 KB
    __shared__ float W1s[40 * 65];    // 10.4 KB
    __shared__ float Xs[9 * 64];
    __shared__ float Ps[9 * 64];
    __shared__ float bw2s[64];
    __shared__ float b2s[64];
    __shared__ float ABs[9];
    __shared__ float G9s[9];
    __shared__ float fcb_s, c0s;
    for (int idx = tid; idx < 64 * 64; idx += 256)
        W2s[(idx >> 6) * 65 + (idx & 63)] = W2[idx];
    for (int idx = tid; idx < 40 * 64; idx += 256)
        W1s[(idx >> 6) * 65 + (idx & 63)] = W1[idx];
    if (tid < 64) { bw2s[tid] = bw2g[tid]; b2s[tid] = b2[tid]; }
    __syncthreads();
    for (int t = tid; t < 576; t += 256) {
        int v = t >> 6, i = t & 63;
        float s = 0.f;
        #pragma unroll 8
        for (int o = 0; o < 64; ++o) s += Xpart[(size_t)o * 576 + v * 64 + i];
        Xs[t] = (v == 0 ? 1.f : -1.f) * s / (float)LL;
    }
    __syncthreads();
    for (int t = tid; t < 576; t += 256) {
        int v = t >> 6, h = t & 63;
        float s = 0.f;
        #pragma unroll 8
        for (int i = 0; i < 64; ++i) s += Xs[v * 64 + i] * W2s[h * 65 + i];
        Ps[t] = s;
    }
    __syncthreads();
    for (int t = tid; t < 9 * F_IN; t += 256) {
        int v = t / F_IN, f = t % F_IN;
        float s = 0.f;
        #pragma unroll 8
        for (int h = 0; h < 64; ++h) s += Ps[v * 64 + h] * W1s[f * 65 + h];
        Mout[t] = s;
    }
    if (tid >= 192 && tid < 201) {
        int v = tid - 192;
        float a = 0.f;
        #pragma unroll 8
        for (int i = 0; i < 64; ++i) a += Xs[v * 64 + i] * bw2s[i];
        ABs[v] = a;
    }
    if (tid >= 208 && tid < 217) {
        int v = tid - 208;
        float g = 0.f;
        #pragma unroll 8
        for (int i = 0; i < 64; ++i)
            g += Xs[v * 64 + i] * (v == 0 ? (float)NN * b2s[i] : b2s[i]);
        G9s[v] = g;
    }
    if (tid == 224) {
        float t2 = 0.f;
        #pragma unroll 8
        for (int o = 0; o < 64; ++o) t2 += fw[o] * cb[o];
        fcb_s = t2 + fb[0];
    }
    __syncthreads();
    if (tid == 0) {
        float c0 = fcb_s;
        #pragma unroll
        for (int v = 0; v < 9; ++v) c0 += G9s[v];
        c0 += ABs[0] * sCsum[0];
        #pragma unroll
        for (int s = 0; s < 8; ++s) {
            float r = 0.f;
            #pragma unroll
            for (int g = 0; g < 16; ++g) r += rpart[s * 16 + g];
            c0 += ABs[1 + s] * r;
        }
        c0s = c0;
    }
    __syncthreads();
    if (tid < BB) out[tid] = c0s;   // seed; kE atomically adds data terms
}

// kE: x-contraction. grid 512 = (b<<6)|pc, block 256, PCH=64 rows/chunk.
__global__ __launch_bounds__(256) void kE(const float* __restrict__ x,
                                          const float* __restrict__ partDf,
                                          const float* __restrict__ partEf,
                                          const float* __restrict__ M,
                                          float* __restrict__ out) {
    __shared__ float xs[64 * F_IN];    // 10.2 KB
    __shared__ float wls[9 * 68];      // padded stride 68
    __shared__ float Ms[9 * F_IN];
    __shared__ float red[256];
    const int b = blockIdx.x >> 6, pc = blockIdx.x & 63;
    const int tid = threadIdx.x;
    const float4* xsrc4 = (const float4*)(x + ((size_t)b * NN + pc * 64) * F_IN);
    float4* xs4 = (float4*)xs;
    for (int idx = tid; idx < 64 * F_IN / 4; idx += 256) xs4[idx] = xsrc4[idx];
    for (int idx = tid; idx < 9 * 16; idx += 256) {
        int v = idx >> 4, j4 = idx & 15;
        float4 s = {0.f, 0.f, 0.f, 0.f};
        if (v == 0) {
            #pragma unroll 8
            for (int y = 0; y < RC; ++y)
                f4add(s, ((const float4*)partDf)[(size_t)y * COL4 + pc * 16 + j4]);
        } else {
            #pragma unroll 8
            for (int y = 0; y < RC; ++y)
                f4add(s, ((const float4*)partEf)[((size_t)y * 8 + (v - 1)) * COL4 + pc * 16 + j4]);
        }
        *(float4*)&wls[v * 68 + j4 * 4] = s;
    }
    for (int idx = tid; idx < 9 * F_IN; idx += 256) Ms[idx] = M[idx];
    __syncthreads();
    float part = 0.f;
    for (int o = tid; o < 9 * F_IN; o += 256) {
        int v = o / F_IN, f = o % F_IN;
        float s = 0.f;
        #pragma unroll 8
        for (int j = 0; j < 64; ++j) s += wls[v * 68 + j] * xs[j * F_IN + f];
        part += Ms[o] * s;
    }
    red[tid] = part;
    __syncthreads();
    for (int off = 128; off > 0; off >>= 1) {
        if (tid < off) red[tid] += red[tid + off];
        __syncthreads();
    }
    if (tid == 0) atomicAdd(&out[b], red[0]);
}

extern "C" void kernel_launch(void* const* d_in, const int* in_sizes, int n_in,
                              void* d_out, int out_size, void* d_ws, size_t ws_size,
                              hipStream_t stream) {
    const float* x  = (const float*)d_in[0];
    const float* A  = (const float*)d_in[1];
    const float* W1 = (const float*)d_in[2];
    const float* b1 = (const float*)d_in[3];
    const float* W2 = (const float*)d_in[4];
    const float* b2 = (const float*)d_in[5];
    const float* cw = (const float*)d_in[6];
    const float* cb = (const float*)d_in[7];
    const float* fw = (const float*)d_in[8];
    const float* fb = (const float*)d_in[9];
    float* out = (float*)d_out;
    float* ws  = (float*)d_ws;

    float* part1 = ws + OFF_P1;
    float* partE = ws + OFF_PE;
    float* partD = ws + OFF_PD;
    float* Xpart = ws + OFF_XP;
    float* bw2   = ws + OFF_BW;
    float* Mmat  = ws + OFF_M;
    float* rpart = ws + OFF_RP;
    float* sCsum = ws + OFF_SCS;

    const float4* A4 = (const float4*)A;

    hipMemsetAsync(sCsum, 0, sizeof(float), stream);   // reset atomic accumulator
    kA<<<dim3(577), dim3(64, 4), 0, stream>>>(A4, A, (float4*)part1, (float4*)partE,
                                              rpart, sCsum, b1, W2, cw, fw, Xpart, bw2);
    kC<<<dim3(513), 256, 0, stream>>>(A4, part1, (float4*)partD, Xpart, bw2, rpart, sCsum,
                                      W1, W2, b2, cb, fw, fb, Mmat, out);
    kE<<<dim3(512), 256, 0, stream>>>(x, partD, partE, Mmat, out);
}